// Round 1
// baseline (1055.845 us; speedup 1.0000x reference)
//
#include <hip/hip_runtime.h>
#include <cstdint>

typedef __attribute__((ext_vector_type(8))) short short8;
typedef __attribute__((ext_vector_type(4))) float f32x4;

#define S_LEN 2048
#define HIDDEN 2048

static __device__ __forceinline__ unsigned short f2bf(float x) {
  union { float f; unsigned int u; } c; c.f = x;
  unsigned int u = c.u;
  unsigned int r = (u + 0x7fffu + ((u >> 16) & 1u)) >> 16;  // RNE
  return (unsigned short)r;
}

// ---------- fp32 -> bf16 elementwise (vectorized x4) ----------
__global__ __launch_bounds__(256) void k_f32_to_bf16(const float* __restrict__ src,
                                                     unsigned short* __restrict__ dst,
                                                     int n4) {
  int i = blockIdx.x * 256 + threadIdx.x;
  if (i >= n4) return;
  float4 v = reinterpret_cast<const float4*>(src)[i];
  ushort4 o;
  o.x = f2bf(v.x); o.y = f2bf(v.y); o.z = f2bf(v.z); o.w = f2bf(v.w);
  reinterpret_cast<ushort4*>(dst)[i] = o;
}

// ---------- transpose (K x N fp32) -> (N x K bf16) ----------
__global__ __launch_bounds__(256) void k_transpose_bf16(const float* __restrict__ src,
                                                        unsigned short* __restrict__ dst,
                                                        int K, int N) {
  __shared__ float tile[32][33];
  int bn = blockIdx.x * 32, bk = blockIdx.y * 32;
  int tx = threadIdx.x & 31, ty = threadIdx.x >> 5;  // ty 0..7
#pragma unroll
  for (int i = 0; i < 32; i += 8)
    tile[ty + i][tx] = src[(size_t)(bk + ty + i) * N + bn + tx];
  __syncthreads();
#pragma unroll
  for (int i = 0; i < 32; i += 8)
    dst[(size_t)(bn + ty + i) * K + bk + tx] = f2bf(tile[tx][ty + i]);
}

// ---------- RoPE in place on (S, nh, 128) fp32 ----------
__global__ __launch_bounds__(256) void k_rope(float* __restrict__ x, int nh) {
  int idx = blockIdx.x * 256 + threadIdx.x;
  int i = idx & 63;
  int h = (idx >> 6) % nh;
  int s = idx / (64 * nh);
  if (s >= S_LEN) return;
  float ex = (float)i / 64.0f;                 // 2i/128, exact
  float freq = powf(10000.0f, -ex);
  float ang = (float)s * freq;
  float sn, cs;
  sincosf(ang, &sn, &cs);
  size_t base = ((size_t)s * nh + h) * 128 + 2 * i;
  float re = x[base], im = x[base + 1];
  x[base]     = re * cs - im * sn;
  x[base + 1] = re * sn + im * cs;
}

// ---------- bf16 MFMA GEMM: C(MxN,f32) = A(MxK,bf16) * Bt(NxK,bf16)^T ----------
// 128x128 tile, 256 threads = 4 waves (2x2), each wave 64x64 via 4x4 frags of 16x16x32.
__global__ __launch_bounds__(256) void k_gemm_bf16(const unsigned short* __restrict__ A,
                                                   const unsigned short* __restrict__ Bt,
                                                   float* __restrict__ C,
                                                   int M, int N, int K) {
  __shared__ short sA[128 * 32];
  __shared__ short sB[128 * 32];
  int tid = threadIdx.x;
  int lane = tid & 63, wid = tid >> 6;
  int wr = wid >> 1, wc = wid & 1;
  int m0 = blockIdx.y * 128, n0 = blockIdx.x * 128;
  f32x4 acc[4][4] = {};

  int ar = tid >> 1;            // staging row 0..127
  int ac = (tid & 1) * 16;      // staging col 0 or 16
  const short8* Ag = (const short8*)(A + (size_t)(m0 + ar) * K + ac);
  const short8* Bg = (const short8*)(Bt + (size_t)(n0 + ar) * K + ac);
  short* sArow = sA + ar * 32 + ac;
  short* sBrow = sB + ar * 32 + ac;

  int kq = (lane >> 4) << 3;    // k offset 0,8,16,24
  int fr = lane & 15;
  const short* aBase = sA + (wr * 64 + fr) * 32 + kq;
  const short* bBase = sB + (wc * 64 + fr) * 32 + kq;

  for (int k0 = 0; k0 < K; k0 += 32) {
    short8 a0 = Ag[0], a1 = Ag[1];
    short8 b0 = Bg[0], b1 = Bg[1];
    __syncthreads();
    *(short8*)(sArow) = a0; *(short8*)(sArow + 8) = a1;
    *(short8*)(sBrow) = b0; *(short8*)(sBrow + 8) = b1;
    __syncthreads();
    short8 af[4], bf4[4];
#pragma unroll
    for (int x = 0; x < 4; x++) {
      af[x]  = *(const short8*)(aBase + x * 16 * 32);
      bf4[x] = *(const short8*)(bBase + x * 16 * 32);
    }
#pragma unroll
    for (int mi = 0; mi < 4; mi++)
#pragma unroll
      for (int ni = 0; ni < 4; ni++)
        acc[mi][ni] = __builtin_amdgcn_mfma_f32_16x16x32_bf16(af[mi], bf4[ni], acc[mi][ni], 0, 0, 0);
    Ag += 4; Bg += 4;
  }

  int col = n0 + wc * 64 + fr;
  int rb = m0 + wr * 64 + ((lane >> 4) << 2);
#pragma unroll
  for (int mi = 0; mi < 4; mi++)
#pragma unroll
    for (int ni = 0; ni < 4; ni++)
#pragma unroll
      for (int j = 0; j < 4; j++)
        C[(size_t)(rb + mi * 16 + j) * N + col + ni * 16] = acc[mi][ni][j];
}

// ---------- fp32 flash attention, GQA, causal ----------
// grid (32 qtiles, 16 heads), 256 threads. QT=64, KT=64.
// Q: (S,16,128) roped f32; K: (S,4,128) roped f32; V: (S,4,128) f32; O: (S,2048) bf16
#define QSTR 140
#define PSTR 66
__global__ __launch_bounds__(256) void k_attn(const float* __restrict__ Q,
                                              const float* __restrict__ K,
                                              const float* __restrict__ V,
                                              unsigned short* __restrict__ O) {
  __shared__ float sQ[64 * QSTR];
  __shared__ float sKV[64 * QSTR];
  __shared__ float sP[64 * PSTR];
  int h = blockIdx.y;
  int qb = (int)gridDim.x - 1 - (int)blockIdx.x;  // long blocks first
  int q0 = qb * 64;
  int kvh = h >> 2;
  int tid = threadIdx.x;

  for (int c = tid; c < 2048; c += 256) {
    int r = c >> 5, d = (c & 31) << 2;
    *(float4*)(sQ + r * QSTR + d) =
        *(const float4*)(Q + (size_t)(q0 + r) * 2048 + h * 128 + d);
  }

  int rg = tid >> 4;        // row group 0..15 (rows rg*4..rg*4+3)
  int r0 = rg << 2;
  int cg = tid & 15;
  int c0s = cg << 2;        // score cols (4)
  int c0v = cg << 3;        // out cols (8)

  float m_i[4], l_i[4], acc[4][8];
#pragma unroll
  for (int i = 0; i < 4; i++) {
    m_i[i] = -3.0e38f; l_i[i] = 0.f;
#pragma unroll
    for (int c = 0; c < 8; c++) acc[i][c] = 0.f;
  }
  const float scale = 0.08838834764831845f;  // 1/sqrt(128)

  for (int kt = 0; kt <= qb; kt++) {
    int k0 = kt * 64;
    __syncthreads();  // previous PV reads of sKV done
    for (int c = tid; c < 2048; c += 256) {
      int r = c >> 5, d = (c & 31) << 2;
      *(float4*)(sKV + r * QSTR + d) =
          *(const float4*)(K + (size_t)(k0 + r) * 512 + kvh * 128 + d);
    }
    __syncthreads();

    float s[4][4];
#pragma unroll
    for (int i = 0; i < 4; i++)
#pragma unroll
      for (int j = 0; j < 4; j++) s[i][j] = 0.f;

    for (int d4 = 0; d4 < 32; d4++) {
      float4 qv[4], kv[4];
#pragma unroll
      for (int i = 0; i < 4; i++) qv[i] = *(const float4*)(sQ + (r0 + i) * QSTR + (d4 << 2));
#pragma unroll
      for (int j = 0; j < 4; j++) kv[j] = *(const float4*)(sKV + (c0s + j) * QSTR + (d4 << 2));
#pragma unroll
      for (int i = 0; i < 4; i++)
#pragma unroll
        for (int j = 0; j < 4; j++)
          s[i][j] += qv[i].x * kv[j].x + qv[i].y * kv[j].y + qv[i].z * kv[j].z + qv[i].w * kv[j].w;
    }

    bool diag = (kt == qb);
#pragma unroll
    for (int i = 0; i < 4; i++)
#pragma unroll
      for (int j = 0; j < 4; j++) {
        s[i][j] *= scale;
        if (diag && (k0 + c0s + j) > (q0 + r0 + i)) s[i][j] = -3.0e38f;
      }

    float tm[4];
#pragma unroll
    for (int i = 0; i < 4; i++)
      tm[i] = fmaxf(fmaxf(s[i][0], s[i][1]), fmaxf(s[i][2], s[i][3]));
    for (int off = 1; off < 16; off <<= 1)
#pragma unroll
      for (int i = 0; i < 4; i++) tm[i] = fmaxf(tm[i], __shfl_xor(tm[i], off));

    float psum[4];
#pragma unroll
    for (int i = 0; i < 4; i++) {
      float mn = fmaxf(m_i[i], tm[i]);
      float sc = __expf(m_i[i] - mn);
      m_i[i] = mn;
      l_i[i] *= sc;
#pragma unroll
      for (int c = 0; c < 8; c++) acc[i][c] *= sc;
      float ps = 0.f;
#pragma unroll
      for (int j = 0; j < 4; j++) {
        float p = __expf(s[i][j] - mn);
        ps += p;
        sP[(r0 + i) * PSTR + c0s + j] = p;
      }
      psum[i] = ps;
    }
    for (int off = 1; off < 16; off <<= 1)
#pragma unroll
      for (int i = 0; i < 4; i++) psum[i] += __shfl_xor(psum[i], off);
#pragma unroll
    for (int i = 0; i < 4; i++) l_i[i] += psum[i];

    __syncthreads();  // sP visible; K reads done
    for (int c = tid; c < 2048; c += 256) {
      int r = c >> 5, d = (c & 31) << 2;
      *(float4*)(sKV + r * QSTR + d) =
          *(const float4*)(V + (size_t)(k0 + r) * 512 + kvh * 128 + d);
    }
    __syncthreads();

    for (int k = 0; k < 64; k++) {
      float pr[4];
#pragma unroll
      for (int i = 0; i < 4; i++) pr[i] = sP[(r0 + i) * PSTR + k];
      float4 v0 = *(const float4*)(sKV + k * QSTR + c0v);
      float4 v1 = *(const float4*)(sKV + k * QSTR + c0v + 4);
#pragma unroll
      for (int i = 0; i < 4; i++) {
        acc[i][0] += pr[i] * v0.x; acc[i][1] += pr[i] * v0.y;
        acc[i][2] += pr[i] * v0.z; acc[i][3] += pr[i] * v0.w;
        acc[i][4] += pr[i] * v1.x; acc[i][5] += pr[i] * v1.y;
        acc[i][6] += pr[i] * v1.z; acc[i][7] += pr[i] * v1.w;
      }
    }
  }

#pragma unroll
  for (int i = 0; i < 4; i++) {
    float inv = 1.0f / l_i[i];
    short8 ov;
#pragma unroll
    for (int c = 0; c < 8; c++) ov[c] = (short)f2bf(acc[i][c] * inv);
    *(short8*)(O + (size_t)(q0 + r0 + i) * 2048 + h * 128 + c0v) = ov;
  }
}

extern "C" void kernel_launch(void* const* d_in, const int* in_sizes, int n_in,
                              void* d_out, int out_size, void* d_ws, size_t ws_size,
                              hipStream_t stream) {
  const float* hs = (const float*)d_in[0];
  const float* wq = (const float*)d_in[1];
  const float* wk = (const float*)d_in[2];
  const float* wv = (const float*)d_in[3];
  const float* wo = (const float*)d_in[4];
  char* ws = (char*)d_ws;

  unsigned short* hb  = (unsigned short*)(ws);             // 2048x2048 bf16   (8 MiB)
  unsigned short* wqt = (unsigned short*)(ws + 8388608);   // 2048x2048 bf16
  unsigned short* wkt = (unsigned short*)(ws + 16777216);  // 512x2048 bf16
  unsigned short* wvt = (unsigned short*)(ws + 18874368);  // 512x2048 bf16
  unsigned short* wot = (unsigned short*)(ws + 20971520);  // 2048x2048 bf16
  float* qf = (float*)(ws + 29360128);                     // 2048x2048 f32
  float* kf = (float*)(ws + 46137344);                     // 2048x512 f32
  float* vf = (float*)(ws + 50331648);                     // 2048x512 f32
  unsigned short* ao = (unsigned short*)(ws + 54525952);   // 2048x2048 bf16
  float* out = (float*)d_out;

  k_f32_to_bf16<<<4096, 256, 0, stream>>>(hs, hb, 2048 * 2048 / 4);
  k_transpose_bf16<<<dim3(64, 64), 256, 0, stream>>>(wq, wqt, 2048, 2048);
  k_transpose_bf16<<<dim3(16, 64), 256, 0, stream>>>(wk, wkt, 2048, 512);
  k_transpose_bf16<<<dim3(16, 64), 256, 0, stream>>>(wv, wvt, 2048, 512);
  k_transpose_bf16<<<dim3(64, 64), 256, 0, stream>>>(wo, wot, 2048, 2048);

  k_gemm_bf16<<<dim3(16, 16), 256, 0, stream>>>(hb, wqt, qf, 2048, 2048, 2048);
  k_gemm_bf16<<<dim3(4, 16), 256, 0, stream>>>(hb, wkt, kf, 2048, 512, 2048);
  k_gemm_bf16<<<dim3(4, 16), 256, 0, stream>>>(hb, wvt, vf, 2048, 512, 2048);

  k_rope<<<(2048 * 16 * 64) / 256, 256, 0, stream>>>(qf, 16);
  k_rope<<<(2048 * 4 * 64) / 256, 256, 0, stream>>>(kf, 4);

  k_attn<<<dim3(32, 16), 256, 0, stream>>>(qf, kf, vf, ao);

  k_gemm_bf16<<<dim3(16, 16), 256, 0, stream>>>(ao, wot, out, 2048, 2048, 2048);
}

// Round 2
// 263.165 us; speedup vs baseline: 4.0121x; 4.0121x over previous
//
#include <hip/hip_runtime.h>
#include <cstdint>

typedef __attribute__((ext_vector_type(8))) short short8;
typedef __attribute__((ext_vector_type(4))) float f32x4;

static __device__ __forceinline__ unsigned short f2bf(float x) {
  union { float f; unsigned int u; } c; c.f = x;
  unsigned int u = c.u;
  unsigned int r = (u + 0x7fffu + ((u >> 16) & 1u)) >> 16;  // RNE
  return (unsigned short)r;
}

static __device__ __forceinline__ void gl_lds16(const void* g, void* l) {
  __builtin_amdgcn_global_load_lds((const __attribute__((address_space(1))) void*)g,
                                   (__attribute__((address_space(3))) void*)l, 16, 0, 0);
}

// ---------- fp32 -> bf16 elementwise (vectorized x4) ----------
__global__ __launch_bounds__(256) void k_f32_to_bf16(const float* __restrict__ src,
                                                     unsigned short* __restrict__ dst,
                                                     int n4) {
  int i = blockIdx.x * 256 + threadIdx.x;
  if (i >= n4) return;
  float4 v = reinterpret_cast<const float4*>(src)[i];
  ushort4 o;
  o.x = f2bf(v.x); o.y = f2bf(v.y); o.z = f2bf(v.z); o.w = f2bf(v.w);
  reinterpret_cast<ushort4*>(dst)[i] = o;
}

// ---------- transpose (K x N fp32, row stride sstride) -> (N x K bf16) ----------
__global__ __launch_bounds__(256) void k_transpose_bf16(const float* __restrict__ src,
                                                        unsigned short* __restrict__ dst,
                                                        int K, int N, int sstride) {
  __shared__ float tile[32][33];
  int bn = blockIdx.x * 32, bk = blockIdx.y * 32;
  int tx = threadIdx.x & 31, ty = threadIdx.x >> 5;  // ty 0..7
#pragma unroll
  for (int i = 0; i < 32; i += 8)
    tile[ty + i][tx] = src[(size_t)(bk + ty + i) * sstride + bn + tx];
  __syncthreads();
#pragma unroll
  for (int i = 0; i < 32; i += 8)
    dst[(size_t)(bn + ty + i) * K + bk + tx] = f2bf(tile[tx][ty + i]);
}

// ---------- RoPE fp32 -> bf16: src (S, sstride) fp32, dst (S, dstride) bf16 ----------
__global__ __launch_bounds__(256) void k_rope_bf16(const float* __restrict__ src,
                                                   unsigned short* __restrict__ dst,
                                                   int nh, int sstride, int dstride) {
  int idx = blockIdx.x * 256 + threadIdx.x;
  int i = idx & 63;
  int h = (idx >> 6) % nh;
  int s = idx / (64 * nh);
  if (s >= 2048) return;
  float freq = powf(10000.0f, -(float)i / 64.0f);
  float ang = (float)s * freq;
  float sn, cs;
  sincosf(ang, &sn, &cs);
  size_t sb = (size_t)s * sstride + h * 128 + 2 * i;
  size_t db = (size_t)s * dstride + h * 128 + 2 * i;
  float re = src[sb], im = src[sb + 1];
  unsigned int lo = f2bf(re * cs - im * sn);
  unsigned int hi = f2bf(re * sn + im * cs);
  *(unsigned int*)(dst + db) = lo | (hi << 16);
}

// ---------- bf16 MFMA GEMM: C(MxN,f32) = A(MxK,bf16) * Bt(NxK,bf16)^T ----------
// 128x128 tile, 256 threads = 4 waves (2x2), global_load_lds width-16 staging (m97).
__global__ __launch_bounds__(256) void k_gemm_bf16(const unsigned short* __restrict__ A,
                                                   const unsigned short* __restrict__ Bt,
                                                   float* __restrict__ C,
                                                   int M, int N, int K) {
  __shared__ short sA[128 * 32];
  __shared__ short sB[128 * 32];
  int tid = threadIdx.x;
  int lane = tid & 63, wid = tid >> 6;
  int wr = wid >> 1, wc = wid & 1;
  int m0 = blockIdx.y * 128, n0 = blockIdx.x * 128;
  f32x4 acc[4][4] = {};

  int gr = tid >> 2;            // row 0..63 (of 64-row half)
  int gc = (tid & 3) * 8;       // short col 0,8,16,24
  const unsigned short* Ag = A + (size_t)(m0 + gr) * K + gc;
  const unsigned short* Bg = Bt + (size_t)(n0 + gr) * K + gc;
  short* lA = sA + (size_t)(tid & ~63) * 8;   // wave-uniform: w*1024 bytes
  short* lB = sB + (size_t)(tid & ~63) * 8;

  int kq = (lane >> 4) << 3;
  int fr = lane & 15;
  const short* aBase = sA + (wr * 64 + fr) * 32 + kq;
  const short* bBase = sB + (wc * 64 + fr) * 32 + kq;

  for (int k0 = 0; k0 < K; k0 += 32) {
    __syncthreads();                       // prev frag reads done
    gl_lds16(Ag + k0,          lA);        // rows 0..63
    gl_lds16(Ag + 64 * K + k0, lA + 2048); // rows 64..127
    gl_lds16(Bg + k0,          lB);
    gl_lds16(Bg + 64 * K + k0, lB + 2048);
    __syncthreads();                       // vmcnt(0) drained before barrier
    short8 af[4], bf4[4];
#pragma unroll
    for (int x = 0; x < 4; x++) {
      af[x]  = *(const short8*)(aBase + x * 16 * 32);
      bf4[x] = *(const short8*)(bBase + x * 16 * 32);
    }
#pragma unroll
    for (int mi = 0; mi < 4; mi++)
#pragma unroll
      for (int ni = 0; ni < 4; ni++)
        acc[mi][ni] = __builtin_amdgcn_mfma_f32_16x16x32_bf16(af[mi], bf4[ni], acc[mi][ni], 0, 0, 0);
  }

  int col = n0 + wc * 64 + fr;
  int rb = m0 + wr * 64 + ((lane >> 4) << 2);
#pragma unroll
  for (int mi = 0; mi < 4; mi++)
#pragma unroll
    for (int ni = 0; ni < 4; ni++)
#pragma unroll
      for (int j = 0; j < 4; j++)
        C[(size_t)(rb + mi * 16 + j) * N + col + ni * 16] = acc[mi][ni][j];
}

// ---------- bf16 MFMA flash attention, GQA, causal ----------
// grid (32 qtiles, 16 heads), 256 thr = 4 waves x 16 q-rows. KV tile 64.
// Qb (2048,2048) bf16 roped; Kb (2048,512) bf16 roped; Vt (512,2048) bf16 (d-major); O (2048,2048) bf16
#define KSTR 136
#define VSTR 72
#define PSTR 72
__global__ __launch_bounds__(256) void k_attn_mfma(const unsigned short* __restrict__ Qb,
                                                   const unsigned short* __restrict__ Kb,
                                                   const unsigned short* __restrict__ Vt,
                                                   unsigned short* __restrict__ O) {
  __shared__ short sK[64 * KSTR];
  __shared__ short sV[128 * VSTR];
  __shared__ short sP[4][16 * PSTR];
  int h = blockIdx.y;
  int qb = (int)gridDim.x - 1 - (int)blockIdx.x;  // long blocks first
  int q0 = qb * 64;
  int kvh = h >> 2;
  int tid = threadIdx.x, lane = tid & 63, w = tid >> 6;
  int fr = lane & 15, g = lane >> 4, kq = g << 3;

  // Q fragments (held in regs for whole block): rows q0 + w*16 + fr
  short8 qf[4];
  {
    const unsigned short* qrow = Qb + (size_t)(q0 + w * 16 + fr) * 2048 + h * 128 + kq;
#pragma unroll
    for (int ko = 0; ko < 4; ko++) qf[ko] = *(const short8*)(qrow + ko * 32);
  }

  f32x4 oacc[8];
#pragma unroll
  for (int nd = 0; nd < 8; nd++) oacc[nd] = (f32x4){0.f, 0.f, 0.f, 0.f};
  float m_i[4] = {-3e38f, -3e38f, -3e38f, -3e38f};
  float l_i[4] = {0.f, 0.f, 0.f, 0.f};
  const float scale = 0.08838834764831845f;  // 1/sqrt(128)

  // staging indices
  int skr = tid >> 2, skc = (tid & 3) << 5;   // K: row 0..63, col {0,32,64,96}
  int svd = tid >> 1, svc = (tid & 1) << 5;   // Vt: d 0..127, col {0,32}
  const unsigned short* Kbase = Kb + (size_t)kvh * 128 + skc;
  const unsigned short* Vbase = Vt + (size_t)(kvh * 128 + svd) * 2048 + svc;
  short* pw = (short*)sP[w];

  for (int kt = 0; kt <= qb; kt++) {
    int k0 = kt * 64;
    __syncthreads();  // prev tile frag reads done
    {
      const short8* src = (const short8*)(Kbase + (size_t)(k0 + skr) * 512);
      short* dst = sK + skr * KSTR + skc;
#pragma unroll
      for (int j = 0; j < 4; j++) *(short8*)(dst + j * 8) = src[j];
    }
    {
      const short8* src = (const short8*)(Vbase + k0);
      short* dst = sV + svd * VSTR + svc;
#pragma unroll
      for (int j = 0; j < 4; j++) *(short8*)(dst + j * 8) = src[j];
    }
    __syncthreads();

    // S = Q K^T
    f32x4 sacc[4];
#pragma unroll
    for (int ni = 0; ni < 4; ni++) sacc[ni] = (f32x4){0.f, 0.f, 0.f, 0.f};
#pragma unroll
    for (int ko = 0; ko < 4; ko++)
#pragma unroll
      for (int ni = 0; ni < 4; ni++) {
        short8 kf = *(const short8*)(sK + (ni * 16 + fr) * KSTR + kq + ko * 32);
        sacc[ni] = __builtin_amdgcn_mfma_f32_16x16x32_bf16(qf[ko], kf, sacc[ni], 0, 0, 0);
      }

    // scale + causal mask; rows q0+w*16+g*4+j, cols k0+ni*16+fr
    int qrow = q0 + w * 16 + (g << 2);
#pragma unroll
    for (int ni = 0; ni < 4; ni++) {
      int kcol = k0 + ni * 16 + fr;
#pragma unroll
      for (int j = 0; j < 4; j++) {
        float s = sacc[ni][j] * scale;
        sacc[ni][j] = (kcol > qrow + j) ? -1e30f : s;
      }
    }

    // online softmax
    float tm[4];
#pragma unroll
    for (int j = 0; j < 4; j++)
      tm[j] = fmaxf(fmaxf(sacc[0][j], sacc[1][j]), fmaxf(sacc[2][j], sacc[3][j]));
#pragma unroll
    for (int off = 1; off < 16; off <<= 1)
#pragma unroll
      for (int j = 0; j < 4; j++) tm[j] = fmaxf(tm[j], __shfl_xor(tm[j], off));

    float mn[4], sc[4], ps[4];
#pragma unroll
    for (int j = 0; j < 4; j++) {
      mn[j] = fmaxf(m_i[j], tm[j]);
      sc[j] = __expf(m_i[j] - mn[j]);
      m_i[j] = mn[j];
      ps[j] = 0.f;
    }
#pragma unroll
    for (int ni = 0; ni < 4; ni++)
#pragma unroll
      for (int j = 0; j < 4; j++) {
        float p = __expf(sacc[ni][j] - mn[j]);
        ps[j] += p;
        pw[((g << 2) + j) * PSTR + ni * 16 + fr] = (short)f2bf(p);
      }
#pragma unroll
    for (int off = 1; off < 16; off <<= 1)
#pragma unroll
      for (int j = 0; j < 4; j++) ps[j] += __shfl_xor(ps[j], off);
#pragma unroll
    for (int j = 0; j < 4; j++) l_i[j] = l_i[j] * sc[j] + ps[j];
#pragma unroll
    for (int nd = 0; nd < 8; nd++)
#pragma unroll
      for (int j = 0; j < 4; j++) oacc[nd][j] *= sc[j];

    // O += P V  (A = P rows fr, B = Vt rows nd*16+fr)
#pragma unroll
    for (int ks = 0; ks < 2; ks++) {
      short8 pa = *(const short8*)(pw + fr * PSTR + kq + ks * 32);
#pragma unroll
      for (int nd = 0; nd < 8; nd++) {
        short8 vb = *(const short8*)(sV + (nd * 16 + fr) * VSTR + kq + ks * 32);
        oacc[nd] = __builtin_amdgcn_mfma_f32_16x16x32_bf16(pa, vb, oacc[nd], 0, 0, 0);
      }
    }
  }

  // epilogue: O rows q0+w*16+g*4+j, col h*128 + nd*16 + fr
  int orow = q0 + w * 16 + (g << 2);
#pragma unroll
  for (int j = 0; j < 4; j++) {
    float inv = 1.0f / l_i[j];
#pragma unroll
    for (int nd = 0; nd < 8; nd++)
      O[(size_t)(orow + j) * 2048 + h * 128 + nd * 16 + fr] = f2bf(oacc[nd][j] * inv);
  }
}

extern "C" void kernel_launch(void* const* d_in, const int* in_sizes, int n_in,
                              void* d_out, int out_size, void* d_ws, size_t ws_size,
                              hipStream_t stream) {
  const float* hs = (const float*)d_in[0];
  const float* wq = (const float*)d_in[1];
  const float* wk = (const float*)d_in[2];
  const float* wv = (const float*)d_in[3];
  const float* wo = (const float*)d_in[4];
  char* ws = (char*)d_ws;

  unsigned short* hb   = (unsigned short*)(ws);             // 2048x2048 bf16 (8MB); later reused as ao
  unsigned short* wqt  = (unsigned short*)(ws + 8388608);   // 2048x2048 bf16; later reused as q_bf
  unsigned short* wkt  = (unsigned short*)(ws + 16777216);  // 512x2048 bf16;  later reused as k_bf
  unsigned short* wvt  = (unsigned short*)(ws + 18874368);  // 512x2048 bf16;  later reused as vt_bf
  unsigned short* wot  = (unsigned short*)(ws + 20971520);  // 2048x2048 bf16
  float* qkvf          = (float*)(ws + 29360128);           // 2048x3072 f32 (25.2MB)
  unsigned short* q_bf = wqt;
  unsigned short* k_bf = wkt;
  unsigned short* vt_bf = wvt;
  unsigned short* ao   = hb;
  float* out = (float*)d_out;

  // hidden -> bf16
  k_f32_to_bf16<<<4096, 256, 0, stream>>>(hs, hb, 2048 * 2048 / 4);
  // weights -> bf16, transposed to (N,K). wqt/wkt/wvt are contiguous -> (3072,2048)
  k_transpose_bf16<<<dim3(64, 64), 256, 0, stream>>>(wq, wqt, 2048, 2048, 2048);
  k_transpose_bf16<<<dim3(16, 64), 256, 0, stream>>>(wk, wkt, 2048, 512, 512);
  k_transpose_bf16<<<dim3(16, 64), 256, 0, stream>>>(wv, wvt, 2048, 512, 512);
  k_transpose_bf16<<<dim3(64, 64), 256, 0, stream>>>(wo, wot, 2048, 2048, 2048);

  // fused QKV projection: (2048x2048) x (3072x2048)^T -> 2048x3072
  k_gemm_bf16<<<dim3(24, 16), 256, 0, stream>>>(hb, wqt, qkvf, 2048, 3072, 2048);

  // RoPE -> bf16 (q cols 0..2047, k cols 2048..2559 of qkvf)
  k_rope_bf16<<<8192, 256, 0, stream>>>(qkvf, q_bf, 16, 3072, 2048);
  k_rope_bf16<<<2048, 256, 0, stream>>>(qkvf + 2048, k_bf, 4, 3072, 512);
  // V (cols 2560..3071) -> transposed bf16 (512 x 2048)
  k_transpose_bf16<<<dim3(16, 64), 256, 0, stream>>>(qkvf + 2560, vt_bf, 2048, 512, 3072);

  k_attn_mfma<<<dim3(32, 16), 256, 0, stream>>>(q_bf, k_bf, vt_bf, ao);

  // output projection
  k_gemm_bf16<<<dim3(16, 16), 256, 0, stream>>>(ao, wot, out, 2048, 2048, 2048);
}

// Round 3
// 197.534 us; speedup vs baseline: 5.3451x; 1.3322x over previous
//
#include <hip/hip_runtime.h>
#include <cstdint>

typedef __attribute__((ext_vector_type(8))) short short8;
typedef __attribute__((ext_vector_type(4))) float f32x4;

static __device__ __forceinline__ unsigned short f2bf(float x) {
  union { float f; unsigned int u; } c; c.f = x;
  unsigned int u = c.u;
  unsigned int r = (u + 0x7fffu + ((u >> 16) & 1u)) >> 16;  // RNE
  return (unsigned short)r;
}

static __device__ __forceinline__ void gl_lds16(const void* g, void* l) {
  __builtin_amdgcn_global_load_lds((const __attribute__((address_space(1))) void*)g,
                                   (__attribute__((address_space(3))) void*)l, 16, 0, 0);
}

// ---------- fp32 -> bf16 elementwise (vectorized x4) ----------
__global__ __launch_bounds__(256) void k_f32_to_bf16(const float* __restrict__ src,
                                                     unsigned short* __restrict__ dst,
                                                     int n4) {
  int i = blockIdx.x * 256 + threadIdx.x;
  if (i >= n4) return;
  float4 v = reinterpret_cast<const float4*>(src)[i];
  ushort4 o;
  o.x = f2bf(v.x); o.y = f2bf(v.y); o.z = f2bf(v.z); o.w = f2bf(v.w);
  reinterpret_cast<ushort4*>(dst)[i] = o;
}

// ---------- transpose (K x N fp32, row stride sstride) -> (N x K bf16) ----------
__global__ __launch_bounds__(256) void k_transpose_bf16(const float* __restrict__ src,
                                                        unsigned short* __restrict__ dst,
                                                        int K, int N, int sstride) {
  __shared__ float tile[32][33];
  int bn = blockIdx.x * 32, bk = blockIdx.y * 32;
  int tx = threadIdx.x & 31, ty = threadIdx.x >> 5;  // ty 0..7
#pragma unroll
  for (int i = 0; i < 32; i += 8)
    tile[ty + i][tx] = src[(size_t)(bk + ty + i) * sstride + bn + tx];
  __syncthreads();
#pragma unroll
  for (int i = 0; i < 32; i += 8)
    dst[(size_t)(bn + ty + i) * K + bk + tx] = f2bf(tile[tx][ty + i]);
}

// ---------- RoPE fp32 -> bf16: src (S, sstride) fp32, dst (S, dstride) bf16 ----------
__global__ __launch_bounds__(256) void k_rope_bf16(const float* __restrict__ src,
                                                   unsigned short* __restrict__ dst,
                                                   int nh, int sstride, int dstride) {
  int idx = blockIdx.x * 256 + threadIdx.x;
  int i = idx & 63;
  int h = (idx >> 6) % nh;
  int s = idx / (64 * nh);
  if (s >= 2048) return;
  float freq = powf(10000.0f, -(float)i / 64.0f);
  float ang = (float)s * freq;
  float sn, cs;
  sincosf(ang, &sn, &cs);
  size_t sb = (size_t)s * sstride + h * 128 + 2 * i;
  size_t db = (size_t)s * dstride + h * 128 + 2 * i;
  float re = src[sb], im = src[sb + 1];
  unsigned int lo = f2bf(re * cs - im * sn);
  unsigned int hi = f2bf(re * sn + im * cs);
  *(unsigned int*)(dst + db) = lo | (hi << 16);
}

// ---------- bf16 MFMA GEMM: C(MxN,f32) = A(MxK,bf16) * Bt(NxK,bf16)^T ----------
// 128x128 tile, 256 threads = 4 waves (2x2). 2-phase double-buffered LDS with
// global_load_lds prefetch one K-step ahead; XOR slot swizzle on both sides.
__global__ __launch_bounds__(256) void k_gemm_bf16(const unsigned short* __restrict__ A,
                                                   const unsigned short* __restrict__ Bt,
                                                   float* __restrict__ C,
                                                   int M, int N, int K) {
  __shared__ short sA[2][128 * 32];
  __shared__ short sB[2][128 * 32];
  int tid = threadIdx.x;
  int lane = tid & 63, wid = tid >> 6;
  int wr = wid >> 1, wc = wid & 1;
  int m0 = blockIdx.y * 128, n0 = blockIdx.x * 128;
  f32x4 acc[4][4] = {};

  // staging: thread tid -> LDS row gr = tid>>2, physical 16B slot s = tid&3.
  // physical slot s holds logical col-slot s ^ ((gr>>1)&3)  (involution)
  int gr = tid >> 2;
  int gcs = ((tid & 3) ^ ((gr >> 1) & 3)) * 8;
  const unsigned short* Ag = A + (size_t)(m0 + gr) * K + gcs;
  const unsigned short* Bg = Bt + (size_t)(n0 + gr) * K + gcs;
  int ldsOff = (tid & ~63) * 8;   // wave-uniform base (shorts)

  // frag reads: row = w*64 + x*16 + fr, logical slot g -> physical g ^ ((fr>>1)&3)
  int kqs = (lane >> 4);          // logical slot g
  int fr = lane & 15;
  int aOff = (wr * 64 + fr) * 32 + ((kqs ^ ((fr >> 1) & 3)) << 3);
  int bOff = (wc * 64 + fr) * 32 + ((kqs ^ ((fr >> 1) & 3)) << 3);

  int nt = K >> 5;
  // prologue: stage tile 0 into buf 0
  gl_lds16(Ag, &sA[0][ldsOff]);
  gl_lds16(Ag + 64 * K, &sA[0][ldsOff + 2048]);
  gl_lds16(Bg, &sB[0][ldsOff]);
  gl_lds16(Bg + 64 * K, &sB[0][ldsOff + 2048]);
  __syncthreads();

  int cur = 0;
  for (int t = 0; t < nt; t++) {
    if (t + 1 < nt) {
      int k0 = (t + 1) << 5;
      gl_lds16(Ag + k0, &sA[cur ^ 1][ldsOff]);
      gl_lds16(Ag + 64 * K + k0, &sA[cur ^ 1][ldsOff + 2048]);
      gl_lds16(Bg + k0, &sB[cur ^ 1][ldsOff]);
      gl_lds16(Bg + 64 * K + k0, &sB[cur ^ 1][ldsOff + 2048]);
    }
    const short* aBase = &sA[cur][aOff];
    const short* bBase = &sB[cur][bOff];
    short8 af[4], bf4[4];
#pragma unroll
    for (int x = 0; x < 4; x++) {
      af[x]  = *(const short8*)(aBase + x * 16 * 32);
      bf4[x] = *(const short8*)(bBase + x * 16 * 32);
    }
#pragma unroll
    for (int mi = 0; mi < 4; mi++)
#pragma unroll
      for (int ni = 0; ni < 4; ni++)
        acc[mi][ni] = __builtin_amdgcn_mfma_f32_16x16x32_bf16(af[mi], bf4[ni], acc[mi][ni], 0, 0, 0);
    __syncthreads();   // drains prefetch vmcnt + orders LDS reuse
    cur ^= 1;
  }

  int col = n0 + wc * 64 + fr;
  int rb = m0 + wr * 64 + ((lane >> 4) << 2);
#pragma unroll
  for (int mi = 0; mi < 4; mi++)
#pragma unroll
    for (int ni = 0; ni < 4; ni++)
#pragma unroll
      for (int j = 0; j < 4; j++)
        C[(size_t)(rb + mi * 16 + j) * N + col + ni * 16] = acc[mi][ni][j];
}

// ---------- bf16 MFMA flash attention, GQA, causal ----------
// grid (32 x-tiles, 16 heads), 256 thr = 4 waves x 16 q-rows. KV tile 64.
// qb remap: h<8 -> x, h>=8 -> 31-x  (complementary work pairing across co-resident blocks)
// Reg-staged K/V prefetch one tile ahead (async-STAGE split).
#define KSTR 136
#define VSTR 72
#define PSTR 72
__global__ __launch_bounds__(256) void k_attn_mfma(const unsigned short* __restrict__ Qb,
                                                   const unsigned short* __restrict__ Kb,
                                                   const unsigned short* __restrict__ Vt,
                                                   unsigned short* __restrict__ O) {
  __shared__ short sK[64 * KSTR];
  __shared__ short sV[128 * VSTR];
  __shared__ short sP[4][16 * PSTR];
  int h = blockIdx.y;
  int x = blockIdx.x;
  int qb = (h < 8) ? x : (31 - x);
  int q0 = qb * 64;
  int kvh = h >> 2;
  int tid = threadIdx.x, lane = tid & 63, w = tid >> 6;
  int fr = lane & 15, g = lane >> 4, kq = g << 3;

  // Q fragments (regs for whole block): rows q0 + w*16 + fr
  short8 qf[4];
  {
    const unsigned short* qrow = Qb + (size_t)(q0 + w * 16 + fr) * 2048 + h * 128 + kq;
#pragma unroll
    for (int ko = 0; ko < 4; ko++) qf[ko] = *(const short8*)(qrow + ko * 32);
  }

  f32x4 oacc[8];
#pragma unroll
  for (int nd = 0; nd < 8; nd++) oacc[nd] = (f32x4){0.f, 0.f, 0.f, 0.f};
  float m_i[4] = {-3e38f, -3e38f, -3e38f, -3e38f};
  float l_i[4] = {0.f, 0.f, 0.f, 0.f};
  const float scale = 0.08838834764831845f;  // 1/sqrt(128)

  // staging indices
  int skr = tid >> 2, skc = (tid & 3) << 5;   // K: row 0..63, shorts {0,32,64,96}
  int svd = tid >> 1, svc = (tid & 1) << 5;   // Vt: d 0..127, shorts {0,32}
  const unsigned short* Kbase = Kb + (size_t)kvh * 128 + skc;
  const unsigned short* Vbase = Vt + (size_t)(kvh * 128 + svd) * 2048 + svc;
  short* pw = (short*)sP[w];
  short* kdst = sK + skr * KSTR + skc;
  short* vdst = sV + svd * VSTR + svc;

  short8 kreg[4], vreg[4];
  {
    const short8* ks = (const short8*)(Kbase + (size_t)skr * 512);
    const short8* vs = (const short8*)(Vbase);
#pragma unroll
    for (int j = 0; j < 4; j++) { kreg[j] = ks[j]; vreg[j] = vs[j]; }
  }

  for (int kt = 0; kt <= qb; kt++) {
    __syncthreads();  // prev tile's LDS reads done
#pragma unroll
    for (int j = 0; j < 4; j++) {
      *(short8*)(kdst + j * 8) = kreg[j];
      *(short8*)(vdst + j * 8) = vreg[j];
    }
    __syncthreads();
    if (kt < qb) {  // prefetch next tile; latency hides under compute below
      int k1 = (kt + 1) * 64;
      const short8* ks = (const short8*)(Kbase + (size_t)(k1 + skr) * 512);
      const short8* vs = (const short8*)(Vbase + k1);
#pragma unroll
      for (int j = 0; j < 4; j++) { kreg[j] = ks[j]; vreg[j] = vs[j]; }
    }

    // S = Q K^T
    f32x4 sacc[4];
#pragma unroll
    for (int ni = 0; ni < 4; ni++) sacc[ni] = (f32x4){0.f, 0.f, 0.f, 0.f};
#pragma unroll
    for (int ko = 0; ko < 4; ko++)
#pragma unroll
      for (int ni = 0; ni < 4; ni++) {
        short8 kf = *(const short8*)(sK + (ni * 16 + fr) * KSTR + kq + ko * 32);
        sacc[ni] = __builtin_amdgcn_mfma_f32_16x16x32_bf16(qf[ko], kf, sacc[ni], 0, 0, 0);
      }

    int qrow = q0 + w * 16 + (g << 2);
    if (kt == qb) {  // diagonal tile: causal mask
      int k0 = kt * 64;
#pragma unroll
      for (int ni = 0; ni < 4; ni++) {
        int kcol = k0 + ni * 16 + fr;
#pragma unroll
        for (int j = 0; j < 4; j++)
          if (kcol > qrow + j) sacc[ni][j] = -3e38f;
      }
    }
#pragma unroll
    for (int ni = 0; ni < 4; ni++)
#pragma unroll
      for (int j = 0; j < 4; j++) sacc[ni][j] *= scale;

    // online softmax
    float tm[4];
#pragma unroll
    for (int j = 0; j < 4; j++)
      tm[j] = fmaxf(fmaxf(sacc[0][j], sacc[1][j]), fmaxf(sacc[2][j], sacc[3][j]));
#pragma unroll
    for (int off = 1; off < 16; off <<= 1)
#pragma unroll
      for (int j = 0; j < 4; j++) tm[j] = fmaxf(tm[j], __shfl_xor(tm[j], off));

    float mn[4], sc[4], ps[4];
#pragma unroll
    for (int j = 0; j < 4; j++) {
      mn[j] = fmaxf(m_i[j], tm[j]);
      sc[j] = __expf(m_i[j] - mn[j]);
      m_i[j] = mn[j];
      ps[j] = 0.f;
    }
#pragma unroll
    for (int ni = 0; ni < 4; ni++)
#pragma unroll
      for (int j = 0; j < 4; j++) {
        float p = __expf(sacc[ni][j] - mn[j]);
        ps[j] += p;
        pw[((g << 2) + j) * PSTR + ni * 16 + fr] = (short)f2bf(p);
      }
#pragma unroll
    for (int off = 1; off < 16; off <<= 1)
#pragma unroll
      for (int j = 0; j < 4; j++) ps[j] += __shfl_xor(ps[j], off);
#pragma unroll
    for (int j = 0; j < 4; j++) l_i[j] = l_i[j] * sc[j] + ps[j];
#pragma unroll
    for (int nd = 0; nd < 8; nd++)
#pragma unroll
      for (int j = 0; j < 4; j++) oacc[nd][j] *= sc[j];

    // O += P V  (A = P rows fr, B = Vt rows nd*16+fr)
#pragma unroll
    for (int ks = 0; ks < 2; ks++) {
      short8 pa = *(const short8*)(pw + fr * PSTR + kq + ks * 32);
#pragma unroll
      for (int nd = 0; nd < 8; nd++) {
        short8 vb = *(const short8*)(sV + (nd * 16 + fr) * VSTR + kq + ks * 32);
        oacc[nd] = __builtin_amdgcn_mfma_f32_16x16x32_bf16(pa, vb, oacc[nd], 0, 0, 0);
      }
    }
  }

  // epilogue
  int orow = q0 + w * 16 + (g << 2);
#pragma unroll
  for (int j = 0; j < 4; j++) {
    float inv = 1.0f / l_i[j];
#pragma unroll
    for (int nd = 0; nd < 8; nd++)
      O[(size_t)(orow + j) * 2048 + h * 128 + nd * 16 + fr] = f2bf(oacc[nd][j] * inv);
  }
}

extern "C" void kernel_launch(void* const* d_in, const int* in_sizes, int n_in,
                              void* d_out, int out_size, void* d_ws, size_t ws_size,
                              hipStream_t stream) {
  const float* hs = (const float*)d_in[0];
  const float* wq = (const float*)d_in[1];
  const float* wk = (const float*)d_in[2];
  const float* wv = (const float*)d_in[3];
  const float* wo = (const float*)d_in[4];
  char* ws = (char*)d_ws;

  unsigned short* hb   = (unsigned short*)(ws);             // 2048x2048 bf16 (8MB); later reused as ao
  unsigned short* wqt  = (unsigned short*)(ws + 8388608);   // 2048x2048 bf16; later reused as q_bf
  unsigned short* wkt  = (unsigned short*)(ws + 16777216);  // 512x2048 bf16;  later reused as k_bf
  unsigned short* wvt  = (unsigned short*)(ws + 18874368);  // 512x2048 bf16;  later reused as vt_bf
  unsigned short* wot  = (unsigned short*)(ws + 20971520);  // 2048x2048 bf16
  float* qkvf          = (float*)(ws + 29360128);           // 2048x3072 f32 (25.2MB)
  unsigned short* q_bf = wqt;
  unsigned short* k_bf = wkt;
  unsigned short* vt_bf = wvt;
  unsigned short* ao   = hb;
  float* out = (float*)d_out;

  // hidden -> bf16
  k_f32_to_bf16<<<4096, 256, 0, stream>>>(hs, hb, 2048 * 2048 / 4);
  // weights -> bf16, transposed to (N,K). wqt/wkt/wvt contiguous -> (3072,2048)
  k_transpose_bf16<<<dim3(64, 64), 256, 0, stream>>>(wq, wqt, 2048, 2048, 2048);
  k_transpose_bf16<<<dim3(16, 64), 256, 0, stream>>>(wk, wkt, 2048, 512, 512);
  k_transpose_bf16<<<dim3(16, 64), 256, 0, stream>>>(wv, wvt, 2048, 512, 512);
  k_transpose_bf16<<<dim3(64, 64), 256, 0, stream>>>(wo, wot, 2048, 2048, 2048);

  // fused QKV projection: (2048x2048) x (3072x2048)^T -> 2048x3072
  k_gemm_bf16<<<dim3(24, 16), 256, 0, stream>>>(hb, wqt, qkvf, 2048, 3072, 2048);

  // RoPE -> bf16 (q cols 0..2047, k cols 2048..2559 of qkvf)
  k_rope_bf16<<<8192, 256, 0, stream>>>(qkvf, q_bf, 16, 3072, 2048);
  k_rope_bf16<<<2048, 256, 0, stream>>>(qkvf + 2048, k_bf, 4, 3072, 512);
  // V (cols 2560..3071) -> transposed bf16 (512 x 2048)
  k_transpose_bf16<<<dim3(16, 64), 256, 0, stream>>>(qkvf + 2560, vt_bf, 2048, 512, 3072);

  k_attn_mfma<<<dim3(32, 16), 256, 0, stream>>>(q_bf, k_bf, vt_bf, ao);

  // output projection
  k_gemm_bf16<<<dim3(16, 16), 256, 0, stream>>>(ao, wot, out, 2048, 2048, 2048);
}

// Round 4
// 179.199 us; speedup vs baseline: 5.8920x; 1.1023x over previous
//
#include <hip/hip_runtime.h>
#include <cstdint>

typedef __attribute__((ext_vector_type(8))) short short8;
typedef __attribute__((ext_vector_type(4))) float f32x4;

static __device__ __forceinline__ unsigned short f2bf(float x) {
  union { float f; unsigned int u; } c; c.f = x;
  unsigned int u = c.u;
  unsigned int r = (u + 0x7fffu + ((u >> 16) & 1u)) >> 16;  // RNE
  return (unsigned short)r;
}

static __device__ __forceinline__ void gl_lds16(const void* g, void* l) {
  __builtin_amdgcn_global_load_lds((const __attribute__((address_space(1))) void*)g,
                                   (__attribute__((address_space(3))) void*)l, 16, 0, 0);
}

// ---------- fp32 -> bf16 elementwise (vectorized x4) ----------
__global__ __launch_bounds__(256) void k_f32_to_bf16(const float* __restrict__ src,
                                                     unsigned short* __restrict__ dst,
                                                     int n4) {
  int i = blockIdx.x * 256 + threadIdx.x;
  if (i >= n4) return;
  float4 v = reinterpret_cast<const float4*>(src)[i];
  ushort4 o;
  o.x = f2bf(v.x); o.y = f2bf(v.y); o.z = f2bf(v.z); o.w = f2bf(v.w);
  reinterpret_cast<ushort4*>(dst)[i] = o;
}

// ---------- single transpose (K x N fp32, row stride sstride) -> (N x K bf16) ----------
__global__ __launch_bounds__(256) void k_transpose_bf16(const float* __restrict__ src,
                                                        unsigned short* __restrict__ dst,
                                                        int K, int N, int sstride) {
  __shared__ float tile[32][33];
  int bn = blockIdx.x * 32, bk = blockIdx.y * 32;
  int tx = threadIdx.x & 31, ty = threadIdx.x >> 5;
#pragma unroll
  for (int i = 0; i < 32; i += 8)
    tile[ty + i][tx] = src[(size_t)(bk + ty + i) * sstride + bn + tx];
  __syncthreads();
#pragma unroll
  for (int i = 0; i < 32; i += 8)
    dst[(size_t)(bn + ty + i) * K + bk + tx] = f2bf(tile[tx][ty + i]);
}

// ---------- fused transpose of all 4 weights (demux by block id) ----------
__global__ __launch_bounds__(256) void k_transpose_all(const float* __restrict__ wq,
                                                       const float* __restrict__ wk,
                                                       const float* __restrict__ wv,
                                                       const float* __restrict__ wo,
                                                       unsigned short* __restrict__ wqt,
                                                       unsigned short* __restrict__ wkt,
                                                       unsigned short* __restrict__ wvt,
                                                       unsigned short* __restrict__ wot) {
  __shared__ float tile[32][33];
  int id = blockIdx.x;
  const float* src; unsigned short* dst; int N, t;
  if (id < 4096)       { src = wq; dst = wqt; N = 2048; t = id; }
  else if (id < 8192)  { src = wo; dst = wot; N = 2048; t = id - 4096; }
  else if (id < 9216)  { src = wk; dst = wkt; N = 512;  t = id - 8192; }
  else                 { src = wv; dst = wvt; N = 512;  t = id - 9216; }
  const int K = 2048;
  int ntx = N >> 5;
  int bn = (t % ntx) * 32, bk = (t / ntx) * 32;
  int tx = threadIdx.x & 31, ty = threadIdx.x >> 5;
#pragma unroll
  for (int i = 0; i < 32; i += 8)
    tile[ty + i][tx] = src[(size_t)(bk + ty + i) * N + bn + tx];
  __syncthreads();
#pragma unroll
  for (int i = 0; i < 32; i += 8)
    dst[(size_t)(bn + ty + i) * K + bk + tx] = f2bf(tile[tx][ty + i]);
}

// ---------- fused RoPE (Q + K) fp32 -> bf16 ----------
// qkvf (2048, 3072): cols 0..2047 = Q (16 heads), 2048..2559 = K (4 heads)
__global__ __launch_bounds__(256) void k_rope_fused(const float* __restrict__ qkvf,
                                                    unsigned short* __restrict__ qd,
                                                    unsigned short* __restrict__ kd) {
  int idx = blockIdx.x * 256 + threadIdx.x;   // 2048*20*64 total
  int i = idx & 63;
  int hh = (idx >> 6) % 20;
  int s = idx / (64 * 20);
  float freq = powf(10000.0f, -(float)i / 64.0f);
  float ang = (float)s * freq;
  float sn, cs;
  sincosf(ang, &sn, &cs);
  size_t sb; unsigned short* dp;
  if (hh < 16) {
    int col = hh * 128 + 2 * i;
    sb = (size_t)s * 3072 + col;
    dp = qd + (size_t)s * 2048 + col;
  } else {
    int col = (hh - 16) * 128 + 2 * i;
    sb = (size_t)s * 3072 + 2048 + col;
    dp = kd + (size_t)s * 512 + col;
  }
  float re = qkvf[sb], im = qkvf[sb + 1];
  unsigned int lo = f2bf(re * cs - im * sn);
  unsigned int hi = f2bf(re * sn + im * cs);
  *(unsigned int*)dp = lo | (hi << 16);
}

// ---------- bf16 MFMA GEMM: C(MxN,f32) = A(MxK,bf16) * Bt(NxK,bf16)^T ----------
// 128(M)x64(N) tile, 256 threads = 4 waves (2x2, each 64x32). 2-phase dbuf LDS,
// global_load_lds width-16, XOR slot swizzle both sides, bijective XCD swizzle.
__global__ __launch_bounds__(256) void k_gemm_bf16(const unsigned short* __restrict__ A,
                                                   const unsigned short* __restrict__ Bt,
                                                   float* __restrict__ C,
                                                   int M, int N, int K) {
  __shared__ short sA[2][128 * 32];
  __shared__ short sB[2][64 * 32];
  int tid = threadIdx.x;
  int lane = tid & 63, wid = tid >> 6;
  int wr = wid >> 1, wc = wid & 1;

  // XCD-aware bijective remap (nwg % 8 == 0 for all our launches)
  int gx = gridDim.x, nwg = gx * gridDim.y;
  int flat = blockIdx.y * gx + blockIdx.x;
  int l = (flat & 7) * (nwg >> 3) + (flat >> 3);
  int bx = l % gx, by = l / gx;
  int m0 = by * 128, n0 = bx * 64;

  f32x4 acc[4][2] = {};

  // staging: chunk c = round*256 + tid -> row c>>2, phys slot c&3.
  // phys slot p at row R holds logical slot p ^ ((R>>1)&3); (R>>1)&3 == (tid>>3)&3 for both rounds
  int gcs = ((tid & 3) ^ ((tid >> 3) & 3)) << 3;
  const unsigned short* Ag0 = A + (size_t)(m0 + (tid >> 2)) * K + gcs;        // rows 0..63
  const unsigned short* Ag1 = A + (size_t)(m0 + 64 + (tid >> 2)) * K + gcs;   // rows 64..127
  const unsigned short* Bg  = Bt + (size_t)(n0 + (tid >> 2)) * K + gcs;       // rows 0..63
  int wb = (tid & ~63) * 8;            // wave-uniform LDS base (shorts)

  // frag reads: logical k-slot g, row R -> phys slot g ^ ((fr>>1)&3)
  int g = lane >> 4, fr = lane & 15;
  int swz = ((g ^ ((fr >> 1) & 3)) << 3);
  int aOff = (wr * 64 + fr) * 32 + swz;
  int bOff = (wc * 32 + fr) * 32 + swz;

  int nt = K >> 5;
  gl_lds16(Ag0, &sA[0][wb]);
  gl_lds16(Ag1, &sA[0][2048 + wb]);
  gl_lds16(Bg,  &sB[0][wb]);
  __syncthreads();

  int cur = 0;
  for (int t = 0; t < nt; t++) {
    if (t + 1 < nt) {
      int k0 = (t + 1) << 5;
      gl_lds16(Ag0 + k0, &sA[cur ^ 1][wb]);
      gl_lds16(Ag1 + k0, &sA[cur ^ 1][2048 + wb]);
      gl_lds16(Bg + k0,  &sB[cur ^ 1][wb]);
    }
    const short* aBase = &sA[cur][aOff];
    const short* bBase = &sB[cur][bOff];
    short8 af[4], bf2[2];
#pragma unroll
    for (int x = 0; x < 4; x++) af[x] = *(const short8*)(aBase + x * 16 * 32);
#pragma unroll
    for (int ni = 0; ni < 2; ni++) bf2[ni] = *(const short8*)(bBase + ni * 16 * 32);
#pragma unroll
    for (int x = 0; x < 4; x++)
#pragma unroll
      for (int ni = 0; ni < 2; ni++)
        acc[x][ni] = __builtin_amdgcn_mfma_f32_16x16x32_bf16(af[x], bf2[ni], acc[x][ni], 0, 0, 0);
    __syncthreads();
    cur ^= 1;
  }

  int col = n0 + wc * 32 + fr;
  int rb = m0 + wr * 64 + (g << 2);
#pragma unroll
  for (int x = 0; x < 4; x++)
#pragma unroll
    for (int ni = 0; ni < 2; ni++)
#pragma unroll
      for (int j = 0; j < 4; j++)
        C[(size_t)(rb + x * 16 + j) * N + col + ni * 16] = acc[x][ni][j];
}

// ---------- bf16 MFMA flash attention, GQA, causal ----------
// grid (32 x-tiles, 16 heads), 256 thr = 4 waves x 16 q-rows. KV tile 64.
// qb remap pairs long+short blocks per CU. Double-buffered K/V LDS, 1 barrier/tile,
// reg prefetch 1 tile ahead, setprio around MFMA clusters.
#define KSTR 136
#define VSTR 72
#define PSTR 72
__global__ __launch_bounds__(256) void k_attn_mfma(const unsigned short* __restrict__ Qb,
                                                   const unsigned short* __restrict__ Kb,
                                                   const unsigned short* __restrict__ Vt,
                                                   unsigned short* __restrict__ O) {
  __shared__ short sK[2][64 * KSTR];
  __shared__ short sV[2][128 * VSTR];
  __shared__ short sP[4][16 * PSTR];
  int h = blockIdx.y;
  int x = blockIdx.x;
  int qb = (h < 8) ? x : (31 - x);
  int q0 = qb * 64;
  int kvh = h >> 2;
  int tid = threadIdx.x, lane = tid & 63, w = tid >> 6;
  int fr = lane & 15, g = lane >> 4, kq = g << 3;

  short8 qf[4];
  {
    const unsigned short* qrow = Qb + (size_t)(q0 + w * 16 + fr) * 2048 + h * 128 + kq;
#pragma unroll
    for (int ko = 0; ko < 4; ko++) qf[ko] = *(const short8*)(qrow + ko * 32);
  }

  f32x4 oacc[8];
#pragma unroll
  for (int nd = 0; nd < 8; nd++) oacc[nd] = (f32x4){0.f, 0.f, 0.f, 0.f};
  float m_i[4] = {-3e38f, -3e38f, -3e38f, -3e38f};
  float l_i[4] = {0.f, 0.f, 0.f, 0.f};
  const float scale = 0.08838834764831845f;

  int skr = tid >> 2, skc = (tid & 3) << 5;
  int svd = tid >> 1, svc = (tid & 1) << 5;
  const unsigned short* Kbase = Kb + (size_t)kvh * 128 + skc;
  const unsigned short* Vbase = Vt + (size_t)(kvh * 128 + svd) * 2048 + svc;
  short* pw = (short*)sP[w];
  int kdOff = skr * KSTR + skc;
  int vdOff = svd * VSTR + svc;

  short8 kreg[4], vreg[4];
  {
    const short8* ks = (const short8*)(Kbase + (size_t)skr * 512);
    const short8* vs = (const short8*)(Vbase);
#pragma unroll
    for (int j = 0; j < 4; j++) { kreg[j] = ks[j]; vreg[j] = vs[j]; }
  }
  // write tile 0 into buf 0
  {
    short* kd = sK[0] + kdOff; short* vd = sV[0] + vdOff;
#pragma unroll
    for (int j = 0; j < 4; j++) { *(short8*)(kd + j * 8) = kreg[j]; *(short8*)(vd + j * 8) = vreg[j]; }
  }
  if (qb >= 1) {  // issue loads for tile 1
    const short8* ks = (const short8*)(Kbase + (size_t)(64 + skr) * 512);
    const short8* vs = (const short8*)(Vbase + 64);
#pragma unroll
    for (int j = 0; j < 4; j++) { kreg[j] = ks[j]; vreg[j] = vs[j]; }
  }
  __syncthreads();

  for (int kt = 0; kt <= qb; kt++) {
    int c = kt & 1;
    const short* sKc = sK[c];
    const short* sVc = sV[c];

    // S = Q K^T
    f32x4 sacc[4];
#pragma unroll
    for (int ni = 0; ni < 4; ni++) sacc[ni] = (f32x4){0.f, 0.f, 0.f, 0.f};
    __builtin_amdgcn_s_setprio(1);
#pragma unroll
    for (int ko = 0; ko < 4; ko++)
#pragma unroll
      for (int ni = 0; ni < 4; ni++) {
        short8 kf = *(const short8*)(sKc + (ni * 16 + fr) * KSTR + kq + ko * 32);
        sacc[ni] = __builtin_amdgcn_mfma_f32_16x16x32_bf16(qf[ko], kf, sacc[ni], 0, 0, 0);
      }
    __builtin_amdgcn_s_setprio(0);

    int qrow = q0 + w * 16 + (g << 2);
    if (kt == qb) {
      int k0 = kt * 64;
#pragma unroll
      for (int ni = 0; ni < 4; ni++) {
        int kcol = k0 + ni * 16 + fr;
#pragma unroll
        for (int j = 0; j < 4; j++)
          if (kcol > qrow + j) sacc[ni][j] = -3e38f;
      }
    }
#pragma unroll
    for (int ni = 0; ni < 4; ni++)
#pragma unroll
      for (int j = 0; j < 4; j++) sacc[ni][j] *= scale;

    // online softmax
    float tm[4];
#pragma unroll
    for (int j = 0; j < 4; j++)
      tm[j] = fmaxf(fmaxf(sacc[0][j], sacc[1][j]), fmaxf(sacc[2][j], sacc[3][j]));
#pragma unroll
    for (int off = 1; off < 16; off <<= 1)
#pragma unroll
      for (int j = 0; j < 4; j++) tm[j] = fmaxf(tm[j], __shfl_xor(tm[j], off));

    float mn[4], sc[4], ps[4];
#pragma unroll
    for (int j = 0; j < 4; j++) {
      mn[j] = fmaxf(m_i[j], tm[j]);
      sc[j] = __expf(m_i[j] - mn[j]);
      m_i[j] = mn[j];
      ps[j] = 0.f;
    }
#pragma unroll
    for (int ni = 0; ni < 4; ni++)
#pragma unroll
      for (int j = 0; j < 4; j++) {
        float p = __expf(sacc[ni][j] - mn[j]);
        ps[j] += p;
        pw[((g << 2) + j) * PSTR + ni * 16 + fr] = (short)f2bf(p);
      }
#pragma unroll
    for (int off = 1; off < 16; off <<= 1)
#pragma unroll
      for (int j = 0; j < 4; j++) ps[j] += __shfl_xor(ps[j], off);
#pragma unroll
    for (int j = 0; j < 4; j++) l_i[j] = l_i[j] * sc[j] + ps[j];
#pragma unroll
    for (int nd = 0; nd < 8; nd++)
#pragma unroll
      for (int j = 0; j < 4; j++) oacc[nd][j] *= sc[j];

    // O += P V
    __builtin_amdgcn_s_setprio(1);
#pragma unroll
    for (int ks = 0; ks < 2; ks++) {
      short8 pa = *(const short8*)(pw + fr * PSTR + kq + ks * 32);
#pragma unroll
      for (int nd = 0; nd < 8; nd++) {
        short8 vb = *(const short8*)(sVc + (nd * 16 + fr) * VSTR + kq + ks * 32);
        oacc[nd] = __builtin_amdgcn_mfma_f32_16x16x32_bf16(pa, vb, oacc[nd], 0, 0, 0);
      }
    }
    __builtin_amdgcn_s_setprio(0);

    if (kt < qb) {
      // write prefetched tile kt+1 into buf c^1 (loads issued one tile ago)
      short* kd = sK[c ^ 1] + kdOff; short* vd = sV[c ^ 1] + vdOff;
#pragma unroll
      for (int j = 0; j < 4; j++) { *(short8*)(kd + j * 8) = kreg[j]; *(short8*)(vd + j * 8) = vreg[j]; }
      if (kt + 1 < qb) {  // issue loads for tile kt+2
        int k2 = (kt + 2) * 64;
        const short8* ks = (const short8*)(Kbase + (size_t)(k2 + skr) * 512);
        const short8* vs = (const short8*)(Vbase + k2);
#pragma unroll
        for (int j = 0; j < 4; j++) { kreg[j] = ks[j]; vreg[j] = vs[j]; }
      }
      __syncthreads();
    }
  }

  int orow = q0 + w * 16 + (g << 2);
#pragma unroll
  for (int j = 0; j < 4; j++) {
    float inv = 1.0f / l_i[j];
#pragma unroll
    for (int nd = 0; nd < 8; nd++)
      O[(size_t)(orow + j) * 2048 + h * 128 + nd * 16 + fr] = f2bf(oacc[nd][j] * inv);
  }
}

extern "C" void kernel_launch(void* const* d_in, const int* in_sizes, int n_in,
                              void* d_out, int out_size, void* d_ws, size_t ws_size,
                              hipStream_t stream) {
  const float* hs = (const float*)d_in[0];
  const float* wq = (const float*)d_in[1];
  const float* wk = (const float*)d_in[2];
  const float* wv = (const float*)d_in[3];
  const float* wo = (const float*)d_in[4];
  char* ws = (char*)d_ws;

  unsigned short* hb   = (unsigned short*)(ws);             // 2048x2048 bf16; later ao
  unsigned short* wqt  = (unsigned short*)(ws + 8388608);   // 2048x2048 bf16; later q_bf
  unsigned short* wkt  = (unsigned short*)(ws + 16777216);  // 512x2048 bf16;  later k_bf
  unsigned short* wvt  = (unsigned short*)(ws + 18874368);  // 512x2048 bf16;  later vt_bf
  unsigned short* wot  = (unsigned short*)(ws + 20971520);  // 2048x2048 bf16
  float* qkvf          = (float*)(ws + 29360128);           // 2048x3072 f32
  unsigned short* q_bf = wqt;
  unsigned short* k_bf = wkt;
  unsigned short* vt_bf = wvt;
  unsigned short* ao   = hb;
  float* out = (float*)d_out;

  k_f32_to_bf16<<<4096, 256, 0, stream>>>(hs, hb, 2048 * 2048 / 4);
  k_transpose_all<<<10240, 256, 0, stream>>>(wq, wk, wv, wo, wqt, wkt, wvt, wot);

  // fused QKV projection: (2048x2048) x (3072x2048)^T -> 2048x3072
  k_gemm_bf16<<<dim3(48, 16), 256, 0, stream>>>(hb, wqt, qkvf, 2048, 3072, 2048);

  k_rope_fused<<<10240, 256, 0, stream>>>(qkvf, q_bf, k_bf);
  // V (cols 2560..3071 of qkvf) -> transposed bf16 (512 x 2048)
  k_transpose_bf16<<<dim3(16, 64), 256, 0, stream>>>(qkvf + 2560, vt_bf, 2048, 512, 3072);

  k_attn_mfma<<<dim3(32, 16), 256, 0, stream>>>(q_bf, k_bf, vt_bf, ao);

  // output projection
  k_gemm_bf16<<<dim3(32, 16), 256, 0, stream>>>(ao, wot, out, 2048, 2048, 2048);
}